// Round 4
// baseline (189.671 us; speedup 1.0000x reference)
//
#include <hip/hip_runtime.h>

#define IMG_H 512
#define IMG_W 512
#define IMG_N (IMG_H * IMG_W)
#define NPLANES 48          // 16 batch * 3 channels
#define TX 64               // output cols per block
#define STRIP 256           // output rows per block
#define RB 8                // rows per iteration
#define RING 26             // LDS ring rows: V reads 18, H writes next 8
#define NITER (STRIP / RB)  // 32
#define SSIM_C1 0.0001f
#define SSIM_C2 0.0009f

// Producer/consumer wave-specialized separable 11x11 Gaussian conv + SSIM.
// Waves 0-1 (tid<128): horizontal conv of 8 new rows -> planar LDS ring.
// Waves 2-3 (tid>=128): vertical conv + SSIM of 8 output rows from the ring.
// One __syncthreads per iteration; ring slots are disjoint between roles.
// Planar LDS (ring[ch][row][col]) keeps every access lane-contiguous: the
// b128 H-writes and b32 V-reads are the patterns that measured 0 bank
// conflicts in R0. Grid = 768 = 3 blocks/CU, all resident (no tail).
__global__ __launch_bounds__(256) void ssim_pipe_kernel(
    const float* __restrict__ pred, const float* __restrict__ target,
    const float* __restrict__ window, float* __restrict__ partial)
{
    __shared__ __align__(16) float ring[5][RING][TX];  // 33,280 B
    __shared__ float gS[16];
    __shared__ float wsum[4];

    const int tid = threadIdx.x;

    // 1D gaussian = row sums of the 2D window (normalized => row sum = g[i])
    if (tid < 11) {
        float s = 0.f;
        #pragma unroll
        for (int j = 0; j < 11; ++j) s += window[tid * 11 + j];
        gS[tid] = s;
    }
    __syncthreads();
    float g[11];
    #pragma unroll
    for (int i = 0; i < 11; ++i) g[i] = gS[i];

    const int plane = blockIdx.z;
    const int y0  = blockIdx.y * STRIP;
    const int tx0 = blockIdx.x * TX;
    const float* pp = pred   + (size_t)plane * IMG_N;
    const float* tp = target + (size_t)plane * IMG_N;

    // Horizontal conv of rel-row `row` (input row y0-5+row), cols 4cg..4cg+3,
    // into ring slot `slot`. 5 aligned predicated float4 loads per array,
    // 4-col register blocking with static tap indices, 5 planar b128 writes.
    auto h_row = [&](int cg, int row, int slot) {
        const int gy = y0 - 5 + row;
        const bool rowok = (gy >= 0) && (gy < IMG_H);
        const float* prow = pp + gy * IMG_W;
        const float* trow = tp + gy * IMG_W;
        float pf[20], tf[20];
        #pragma unroll
        for (int q = 0; q < 5; ++q) {
            const int cbase = tx0 + 4 * cg - 8 + 4 * q;   // multiple of 4
            const bool ok = rowok && (cbase >= 0) && (cbase < IMG_W);
            float4 p4 = ok ? *(const float4*)(prow + cbase) : make_float4(0, 0, 0, 0);
            float4 t4 = ok ? *(const float4*)(trow + cbase) : make_float4(0, 0, 0, 0);
            pf[4*q+0] = p4.x; pf[4*q+1] = p4.y; pf[4*q+2] = p4.z; pf[4*q+3] = p4.w;
            tf[4*q+0] = t4.x; tf[4*q+1] = t4.y; tf[4*q+2] = t4.z; tf[4*q+3] = t4.w;
        }
        float m1[4], m2[4], e11[4], e22[4], e12[4];
        #pragma unroll
        for (int o = 0; o < 4; ++o) {
            m1[o] = 0.f; m2[o] = 0.f; e11[o] = 0.f; e22[o] = 0.f; e12[o] = 0.f;
        }
        #pragma unroll
        for (int j = 3; j <= 16; ++j) {       // pf[j] = col 4cg-8+j
            const float p = pf[j], t = tf[j];
            const float p2 = p * p, t2 = t * t, pt = p * t;
            #pragma unroll
            for (int o = 0; o < 4; ++o) {
                const int k = j - 3 - o;      // compile-time tap index
                if (k >= 0 && k < 11) {
                    const float w = g[k];
                    m1[o]  = fmaf(w, p,  m1[o]);
                    m2[o]  = fmaf(w, t,  m2[o]);
                    e11[o] = fmaf(w, p2, e11[o]);
                    e22[o] = fmaf(w, t2, e22[o]);
                    e12[o] = fmaf(w, pt, e12[o]);
                }
            }
        }
        const int c4 = 4 * cg;
        *(float4*)&ring[0][slot][c4] = make_float4(m1[0],  m1[1],  m1[2],  m1[3]);
        *(float4*)&ring[1][slot][c4] = make_float4(m2[0],  m2[1],  m2[2],  m2[3]);
        *(float4*)&ring[2][slot][c4] = make_float4(e11[0], e11[1], e11[2], e11[3]);
        *(float4*)&ring[3][slot][c4] = make_float4(e12[0], e12[1], e12[2], e12[3]);
        *(float4*)&ring[4][slot][c4] = make_float4(e22[0], e22[1], e22[2], e22[3]);
    };

    // Prologue: all 256 threads fill ring rows 0..17
    {
        const int pcg = tid & 15, prow = tid >> 4;    // 16 rows x 16 cgs
        h_row(pcg, prow, prow);                       // rows 0..15
        if (prow < 2) h_row(pcg, 16 + prow, 16 + prow);
    }
    __syncthreads();

    float acc = 0.f;
    int sbH = 18;   // (18 + 8*it) % RING
    int sbV = 0;    // (8*it) % RING

    #pragma unroll 1
    for (int it = 0; it < NITER; ++it) {
        if (tid < 128) {
            // ---- producer: H rows 8it+18 .. 8it+25 (skip past row 265) ----
            if (it < NITER - 1) {
                const int cg = tid & 15, hrow = tid >> 4;     // hrow 0..7
                int slot = sbH + hrow; if (slot >= RING) slot -= RING;
                h_row(cg, 18 + it * 8 + hrow, slot);
            }
        } else {
            // ---- consumer: V conv + SSIM for output rows 8it .. 8it+7 ----
            const int vt = tid - 128;
            const int vcol = vt & 63;
            const int vrg  = vt >> 6;          // 0..1, rows 4vrg..4vrg+3
            int s0 = sbV + 4 * vrg; if (s0 >= RING) s0 -= RING;
            float a0[4], a1[4], a2[4], a3[4], a4[4];
            #pragma unroll
            for (int j = 0; j < 4; ++j) {
                a0[j] = 0.f; a1[j] = 0.f; a2[j] = 0.f; a3[j] = 0.f; a4[j] = 0.f;
            }
            #pragma unroll
            for (int r = 0; r < 14; ++r) {
                int s = s0 + r; if (s >= RING) s -= RING;
                const float v0 = ring[0][s][vcol];
                const float v1 = ring[1][s][vcol];
                const float v2 = ring[2][s][vcol];
                const float v3 = ring[3][s][vcol];
                const float v4 = ring[4][s][vcol];
                #pragma unroll
                for (int j = 0; j < 4; ++j) {
                    const int k = r - j;       // compile-time tap index
                    if (k >= 0 && k < 11) {
                        const float w = g[k];
                        a0[j] = fmaf(w, v0, a0[j]);
                        a1[j] = fmaf(w, v1, a1[j]);
                        a2[j] = fmaf(w, v2, a2[j]);
                        a3[j] = fmaf(w, v3, a3[j]);
                        a4[j] = fmaf(w, v4, a4[j]);
                    }
                }
            }
            #pragma unroll
            for (int j = 0; j < 4; ++j) {
                const float mu1 = a0[j], mu2 = a1[j];
                const float mu1_sq = mu1 * mu1, mu2_sq = mu2 * mu2;
                const float mu1_mu2 = mu1 * mu2;
                const float s1  = a2[j] - mu1_sq;     // E11 - mu1^2
                const float s2  = a4[j] - mu2_sq;     // E22 - mu2^2
                const float s12 = a3[j] - mu1_mu2;    // E12 - mu1*mu2
                const float num = (2.f * mu1_mu2 + SSIM_C1) * (2.f * s12 + SSIM_C2);
                const float den = (mu1_sq + mu2_sq + SSIM_C1) * (s1 + s2 + SSIM_C2);
                acc += num * __builtin_amdgcn_rcpf(den);
            }
        }
        __syncthreads();
        sbH += RB; if (sbH >= RING) sbH -= RING;
        sbV += RB; if (sbV >= RING) sbV -= RING;
    }

    // Block reduction (H waves contribute 0)
    #pragma unroll
    for (int off = 32; off > 0; off >>= 1)
        acc += __shfl_down(acc, off, 64);
    if ((tid & 63) == 0) wsum[tid >> 6] = acc;
    __syncthreads();
    if (tid == 0) {
        const int bid = blockIdx.x + gridDim.x * (blockIdx.y + gridDim.y * blockIdx.z);
        partial[bid] = wsum[0] + wsum[1] + wsum[2] + wsum[3];
    }
}

// Reduce 768 partials -> scalar (double accumulate)
__global__ __launch_bounds__(256) void ssim_reduce_kernel(
    const float* __restrict__ partial, float* __restrict__ out)
{
    const int tid = threadIdx.x;
    float s = partial[tid] + partial[tid + 256] + partial[tid + 512];
    double acc = (double)s;
    #pragma unroll
    for (int off = 32; off > 0; off >>= 1)
        acc += __shfl_down(acc, off, 64);
    __shared__ double wsumd[4];
    const int lane = tid & 63, wid = tid >> 6;
    if (lane == 0) wsumd[wid] = acc;
    __syncthreads();
    if (tid == 0) {
        const double total = wsumd[0] + wsumd[1] + wsumd[2] + wsumd[3];
        const double N = (double)NPLANES * IMG_H * IMG_W;
        out[0] = (float)(1.0 - total / N);
    }
}

extern "C" void kernel_launch(void* const* d_in, const int* in_sizes, int n_in,
                              void* d_out, int out_size, void* d_ws, size_t ws_size,
                              hipStream_t stream)
{
    const float* pred   = (const float*)d_in[0];
    const float* target = (const float*)d_in[1];
    const float* window = (const float*)d_in[2];
    float* out = (float*)d_out;
    float* partial = (float*)d_ws;   // 768 floats = 3 KiB

    dim3 grid(IMG_W / TX, IMG_H / STRIP, NPLANES);   // (8, 2, 48) = 768 blocks
    ssim_pipe_kernel<<<grid, 256, 0, stream>>>(pred, target, window, partial);
    ssim_reduce_kernel<<<1, 256, 0, stream>>>(partial, out);
}

// Round 5
// 184.619 us; speedup vs baseline: 1.0274x; 1.0274x over previous
//
#include <hip/hip_runtime.h>

#define IMG_H 512
#define IMG_W 512
#define IMG_N (IMG_H * IMG_W)
#define NPLANES 48          // 16 batch * 3 channels
#define TX 64               // output cols per block
#define STRIP 256           // output rows per block
#define RB 8                // rows per iteration
#define RING 26             // LDS ring rows: V reads 18, H writes the other 8
#define NITER (STRIP / RB)  // 32 (even)
#define SSIM_C1 0.0001f
#define SSIM_C2 0.0009f

// Barrier that drains LDS only: prefetch global loads stay in flight across
// it (HIP __syncthreads emits s_waitcnt vmcnt(0) which would kill the
// software pipeline). Correct here: all in-flight vmem ops are consumed by
// the issuing wave itself (compiler inserts vmcnt waits before use).
__device__ __forceinline__ void barrier_lgkm() {
    asm volatile("s_waitcnt lgkmcnt(0)\n\ts_barrier" ::: "memory");
}

// Producer/consumer wave-specialized separable 11x11 Gaussian conv + SSIM,
// with 2-deep ping-pong register prefetch on the producer side.
// Waves 0-1 (tid<128): horizontal conv of 8 new rows -> planar LDS ring.
// Waves 2-3 (tid>=128): vertical conv + SSIM of 8 output rows from the ring.
__global__ __launch_bounds__(256) void ssim_pipe_kernel(
    const float* __restrict__ pred, const float* __restrict__ target,
    const float* __restrict__ window, float* __restrict__ partial)
{
    __shared__ __align__(16) float ring[5][RING][TX];  // 33,280 B
    __shared__ float gS[16];
    __shared__ float wsum[4];

    const int tid = threadIdx.x;

    // 1D gaussian = row sums of the 2D window (normalized => row sum = g[i])
    if (tid < 11) {
        float s = 0.f;
        #pragma unroll
        for (int j = 0; j < 11; ++j) s += window[tid * 11 + j];
        gS[tid] = s;
    }
    __syncthreads();
    float g[11];
    #pragma unroll
    for (int i = 0; i < 11; ++i) g[i] = gS[i];

    const int plane = blockIdx.z;
    const int y0  = blockIdx.y * STRIP;
    const int tx0 = blockIdx.x * TX;
    const float* pp = pred   + (size_t)plane * IMG_N;
    const float* tp = target + (size_t)plane * IMG_N;

    // H-role geometry (also used by the all-thread prologue)
    const int cg   = tid & 15;       // column group: cols 4cg..4cg+3
    const int hrow = tid >> 4;       // prologue: 0..15; main loop (tid<128): 0..7

    // Iteration-invariant column offsets/predicates for the 5 float4 loads
    int  coff[5];
    bool colok[5];
    #pragma unroll
    for (int q = 0; q < 5; ++q) {
        coff[q]  = tx0 + 4 * cg - 8 + 4 * q;             // multiple of 4
        colok[q] = (unsigned)coff[q] < (unsigned)IMG_W;  // catches <0 too
    }

    // Raw global loads for rel-row `row` (input row y0-5+row): 5 predicated
    // aligned float4 per array.
    auto h_load = [&](int row, float4* bp, float4* bt) {
        const int gy = y0 - 5 + row;
        const bool rok = (unsigned)gy < (unsigned)IMG_H;
        const float* prow = pp + gy * IMG_W;
        const float* trow = tp + gy * IMG_W;
        #pragma unroll
        for (int q = 0; q < 5; ++q) {
            const bool ok = rok && colok[q];
            bp[q] = ok ? *(const float4*)(prow + coff[q]) : make_float4(0, 0, 0, 0);
            bt[q] = ok ? *(const float4*)(trow + coff[q]) : make_float4(0, 0, 0, 0);
        }
    };

    // Horizontal conv (4-col register blocking, static tap indices) from the
    // prefetched raw registers into ring slot `slot` (5 planar b128 writes).
    auto h_compute = [&](const float4* bp, const float4* bt, int slot) {
        float pf[20], tf[20];
        #pragma unroll
        for (int q = 0; q < 5; ++q) {
            pf[4*q+0] = bp[q].x; pf[4*q+1] = bp[q].y;
            pf[4*q+2] = bp[q].z; pf[4*q+3] = bp[q].w;
            tf[4*q+0] = bt[q].x; tf[4*q+1] = bt[q].y;
            tf[4*q+2] = bt[q].z; tf[4*q+3] = bt[q].w;
        }
        float m1[4], m2[4], e11[4], e22[4], e12[4];
        #pragma unroll
        for (int o = 0; o < 4; ++o) {
            m1[o] = 0.f; m2[o] = 0.f; e11[o] = 0.f; e22[o] = 0.f; e12[o] = 0.f;
        }
        #pragma unroll
        for (int j = 3; j <= 16; ++j) {       // pf[j] = col 4cg-8+j
            const float p = pf[j], t = tf[j];
            const float p2 = p * p, t2 = t * t, pt = p * t;
            #pragma unroll
            for (int o = 0; o < 4; ++o) {
                const int k = j - 3 - o;      // compile-time tap index
                if (k >= 0 && k < 11) {
                    const float w = g[k];
                    m1[o]  = fmaf(w, p,  m1[o]);
                    m2[o]  = fmaf(w, t,  m2[o]);
                    e11[o] = fmaf(w, p2, e11[o]);
                    e22[o] = fmaf(w, t2, e22[o]);
                    e12[o] = fmaf(w, pt, e12[o]);
                }
            }
        }
        const int c4 = 4 * cg;
        *(float4*)&ring[0][slot][c4] = make_float4(m1[0],  m1[1],  m1[2],  m1[3]);
        *(float4*)&ring[1][slot][c4] = make_float4(m2[0],  m2[1],  m2[2],  m2[3]);
        *(float4*)&ring[2][slot][c4] = make_float4(e11[0], e11[1], e11[2], e11[3]);
        *(float4*)&ring[3][slot][c4] = make_float4(e12[0], e12[1], e12[2], e12[3]);
        *(float4*)&ring[4][slot][c4] = make_float4(e22[0], e22[1], e22[2], e22[3]);
    };

    // V-role geometry
    const int vt   = tid - 128;
    const int vcol = vt & 63;
    const int vrg  = vt >> 6;        // 0..1, rows 4vrg..4vrg+3

    float acc = 0.f;

    // Vertical conv + SSIM for output rows at ring base sbVc
    auto do_V = [&](int sbVc) {
        int s0 = sbVc + 4 * vrg; if (s0 >= RING) s0 -= RING;
        float a0[4], a1[4], a2[4], a3[4], a4[4];
        #pragma unroll
        for (int j = 0; j < 4; ++j) {
            a0[j] = 0.f; a1[j] = 0.f; a2[j] = 0.f; a3[j] = 0.f; a4[j] = 0.f;
        }
        #pragma unroll
        for (int r = 0; r < 14; ++r) {
            int s = s0 + r; if (s >= RING) s -= RING;
            const float v0 = ring[0][s][vcol];
            const float v1 = ring[1][s][vcol];
            const float v2 = ring[2][s][vcol];
            const float v3 = ring[3][s][vcol];
            const float v4 = ring[4][s][vcol];
            #pragma unroll
            for (int j = 0; j < 4; ++j) {
                const int k = r - j;          // compile-time tap index
                if (k >= 0 && k < 11) {
                    const float w = g[k];
                    a0[j] = fmaf(w, v0, a0[j]);
                    a1[j] = fmaf(w, v1, a1[j]);
                    a2[j] = fmaf(w, v2, a2[j]);
                    a3[j] = fmaf(w, v3, a3[j]);
                    a4[j] = fmaf(w, v4, a4[j]);
                }
            }
        }
        #pragma unroll
        for (int j = 0; j < 4; ++j) {
            const float mu1 = a0[j], mu2 = a1[j];
            const float mu1_sq = mu1 * mu1, mu2_sq = mu2 * mu2;
            const float mu1_mu2 = mu1 * mu2;
            const float s1  = a2[j] - mu1_sq;     // E11 - mu1^2
            const float s2  = a4[j] - mu2_sq;     // E22 - mu2^2
            const float s12 = a3[j] - mu1_mu2;    // E12 - mu1*mu2
            const float num = (2.f * mu1_mu2 + SSIM_C1) * (2.f * s12 + SSIM_C2);
            const float den = (mu1_sq + mu2_sq + SSIM_C1) * (s1 + s2 + SSIM_C2);
            acc += num * __builtin_amdgcn_rcpf(den);
        }
    };

    // ---- Prologue: all 256 threads fill ring rows 0..17 ----
    {
        float4 bp[5], bt[5];
        h_load(hrow, bp, bt);
        h_compute(bp, bt, hrow);                 // rows 0..15
        if (hrow < 2) {
            h_load(16 + hrow, bp, bt);
            h_compute(bp, bt, 16 + hrow);        // rows 16,17
        }
    }

    // Preload iters 0 and 1 into the ping-pong buffers (H threads only)
    float4 pA[5], tA[5], pB[5], tB[5];
    if (tid < 128) {
        h_load(18 + hrow, pA, tA);               // iter 0: rows 18..25
        h_load(26 + hrow, pB, tB);               // iter 1: rows 26..33
    }
    barrier_lgkm();

    int sbH = 18, sbV = 0;

    // H computes at iters 0..NITER-2; load for iter j (j<NITER-1) is issued
    // at iter j-2 into the buffer just consumed.
    #pragma unroll 1
    for (int it = 0; it < NITER; it += 2) {
        // ---- even sub-iteration (logical iter `it`, buffer A) ----
        if (tid < 128) {
            if (it < NITER - 1) {
                int slot = sbH + hrow; if (slot >= RING) slot -= RING;
                h_compute(pA, tA, slot);
                if (it + 2 < NITER - 1)
                    h_load(18 + (it + 2) * 8 + hrow, pA, tA);
            }
        } else {
            do_V(sbV);
        }
        sbH += RB; if (sbH >= RING) sbH -= RING;
        sbV += RB; if (sbV >= RING) sbV -= RING;
        barrier_lgkm();

        // ---- odd sub-iteration (logical iter `it+1`, buffer B) ----
        if (tid < 128) {
            if (it + 1 < NITER - 1) {
                int slot = sbH + hrow; if (slot >= RING) slot -= RING;
                h_compute(pB, tB, slot);
                if (it + 3 < NITER - 1)
                    h_load(18 + (it + 3) * 8 + hrow, pB, tB);
            }
        } else {
            do_V(sbV);
        }
        sbH += RB; if (sbH >= RING) sbH -= RING;
        sbV += RB; if (sbV >= RING) sbV -= RING;
        barrier_lgkm();
    }

    // Block reduction (H waves contribute 0)
    #pragma unroll
    for (int off = 32; off > 0; off >>= 1)
        acc += __shfl_down(acc, off, 64);
    if ((tid & 63) == 0) wsum[tid >> 6] = acc;
    __syncthreads();
    if (tid == 0) {
        const int bid = blockIdx.x + gridDim.x * (blockIdx.y + gridDim.y * blockIdx.z);
        partial[bid] = wsum[0] + wsum[1] + wsum[2] + wsum[3];
    }
}

// Reduce 768 partials -> scalar (double accumulate)
__global__ __launch_bounds__(256) void ssim_reduce_kernel(
    const float* __restrict__ partial, float* __restrict__ out)
{
    const int tid = threadIdx.x;
    float s = partial[tid] + partial[tid + 256] + partial[tid + 512];
    double acc = (double)s;
    #pragma unroll
    for (int off = 32; off > 0; off >>= 1)
        acc += __shfl_down(acc, off, 64);
    __shared__ double wsumd[4];
    const int lane = tid & 63, wid = tid >> 6;
    if (lane == 0) wsumd[wid] = acc;
    __syncthreads();
    if (tid == 0) {
        const double total = wsumd[0] + wsumd[1] + wsumd[2] + wsumd[3];
        const double N = (double)NPLANES * IMG_H * IMG_W;
        out[0] = (float)(1.0 - total / N);
    }
}

extern "C" void kernel_launch(void* const* d_in, const int* in_sizes, int n_in,
                              void* d_out, int out_size, void* d_ws, size_t ws_size,
                              hipStream_t stream)
{
    const float* pred   = (const float*)d_in[0];
    const float* target = (const float*)d_in[1];
    const float* window = (const float*)d_in[2];
    float* out = (float*)d_out;
    float* partial = (float*)d_ws;   // 768 floats = 3 KiB

    dim3 grid(IMG_W / TX, IMG_H / STRIP, NPLANES);   // (8, 2, 48) = 768 blocks
    ssim_pipe_kernel<<<grid, 256, 0, stream>>>(pred, target, window, partial);
    ssim_reduce_kernel<<<1, 256, 0, stream>>>(partial, out);
}

// Round 7
// 155.955 us; speedup vs baseline: 1.2162x; 1.1838x over previous
//
#include <hip/hip_runtime.h>
#include <hip/hip_bf16.h>

#define IMG_H 512
#define IMG_W 512
#define IMG_N (IMG_H * IMG_W)
#define NPLANES 48          // 16 batch * 3 channels
#define TILE 64             // 64x64 output tile per block
#define XS 88               // LDS row stride (elements); 176 B = 2-way banks (free)
#define SSIM_C1 0.0001f
#define SSIM_C2 0.0009f

typedef __attribute__((ext_vector_type(8))) short bf16x8;   // 8 bf16 = 4 VGPR
typedef __attribute__((ext_vector_type(4))) float f32x4;

// RNE float->bf16 (bits), branch-free
__device__ __forceinline__ unsigned bf16r(float x) {
    unsigned u = __float_as_uint(x);
    return (u + 0x7fffu + ((u >> 16) & 1u)) >> 16;
}
__device__ __forceinline__ unsigned pk2(float a, float b) {
    return bf16r(a) | (bf16r(b) << 16);       // a -> low half
}
__device__ __forceinline__ float lo16(unsigned u) { return __uint_as_float(u << 16); }
__device__ __forceinline__ float hi16(unsigned u) { return __uint_as_float(u & 0xffff0000u); }
__device__ __forceinline__ unsigned sqpk(unsigned u) {
    float a = lo16(u), b = hi16(u); return pk2(a * a, b * b);
}
__device__ __forceinline__ unsigned mulpk(unsigned u, unsigned v) {
    return pk2(lo16(u) * lo16(v), hi16(u) * hi16(v));
}

// Separable 11x11 Gaussian conv via MFMA. Per block: 64x64 outputs.
// Stage X rows/cols [base-8, base+71] as bf16 (p,t). Per channel (p,t,p2,t2,pt):
//   H-pass: D[16r x 16c] = X * Wh  (Wh[k][j] = g[k-j-3], banded, in registers)
//   store H transposed (C-layout rows are contiguous) -> Ht[col][hrow]
//   V-pass: D = Wv * Ht-frag (Wv = same register fragment), accumulate in VGPRs.
// Each wave owns 16 output cols end-to-end => no barriers in the channel loop.
__global__ __launch_bounds__(256) void ssim_mfma_kernel(
    const float* __restrict__ pred, const float* __restrict__ target,
    const float* __restrict__ window, float* __restrict__ partial)
{
    __shared__ unsigned short Xp[80 * XS];   // 14080 B
    __shared__ unsigned short Xt[80 * XS];   // 14080 B
    __shared__ unsigned short Ht[64 * XS];   // 11264 B
    __shared__ unsigned short gbfS[16];      // bf16 taps, [11..15] = 0
    __shared__ float wsum[4];

    const int tid  = threadIdx.x;
    const int w    = tid >> 6;       // wave = col-tile (16 cols)
    const int lane = tid & 63;
    const int n15  = lane & 15;
    const int quad = lane >> 4;

    // bf16 tap table: g[i] = row sums of the normalized 2D window
    if (tid < 16) {
        float gv = 0.f;
        if (tid < 11) {
            float s = 0.f;
            #pragma unroll
            for (int j = 0; j < 11; ++j) s += window[tid * 11 + j];
            gv = s;
        }
        gbfS[tid] = (unsigned short)bf16r(gv);
    }

    const int plane  = blockIdx.z;
    const int base_r = blockIdx.y * TILE;
    const int base_c = blockIdx.x * TILE;
    const float* pp = pred   + (size_t)plane * IMG_N;
    const float* tp = target + (size_t)plane * IMG_N;

    // ---- Stage p,t as bf16: rows/cols [base-8, base+71], zero outside ----
    #pragma unroll
    for (int i = 0; i < 7; ++i) {
        const unsigned fi = (unsigned)tid + 256u * i;   // 80 rows x 20 float4
        if (fi < 1600u) {
            const unsigned ri = fi / 20u, q = fi - 20u * ri;
            const int gr = base_r - 8 + (int)ri;
            const int gc = base_c - 8 + 4 * (int)q;
            const bool ok = ((unsigned)gr < (unsigned)IMG_H) &&
                            ((unsigned)gc < (unsigned)IMG_W);
            const float4 z4 = make_float4(0.f, 0.f, 0.f, 0.f);
            float4 p4 = ok ? *(const float4*)(pp + gr * IMG_W + gc) : z4;
            float4 t4 = ok ? *(const float4*)(tp + gr * IMG_W + gc) : z4;
            const int off = (int)ri * XS + 4 * (int)q;   // 8B-aligned
            *(uint2*)&Xp[off] = make_uint2(pk2(p4.x, p4.y), pk2(p4.z, p4.w));
            *(uint2*)&Xt[off] = make_uint2(pk2(t4.x, t4.y), pk2(t4.z, t4.w));
        }
    }
    __syncthreads();

    // ---- Weight fragment: element j holds g[8*quad + j - n15 - 3] (or 0).
    // Serves as B-operand (Wh[k][n]) in H-pass and A-operand (Wv[m][k]) in V.
    uint4 wu;
    {
        unsigned wd[4];
        #pragma unroll
        for (int d = 0; d < 4; ++d) {
            const int t0 = 8 * quad + 2 * d - n15 - 3;
            const unsigned lo = gbfS[((unsigned)t0       <= 10u) ? t0       : 11];
            const unsigned hi = gbfS[((unsigned)(t0 + 1) <= 10u) ? (t0 + 1) : 11];
            wd[d] = lo | (hi << 16);
        }
        wu = make_uint4(wd[0], wd[1], wd[2], wd[3]);
    }
    const bf16x8 wfrag = __builtin_bit_cast(bf16x8, wu);
    const f32x4 zero4 = {0.f, 0.f, 0.f, 0.f};

    f32x4 vacc[5][4];
    #pragma unroll
    for (int c = 0; c < 5; ++c)
        #pragma unroll
        for (int r = 0; r < 4; ++r) vacc[c][r] = zero4;

    #pragma unroll
    for (int ch = 0; ch < 5; ++ch) {
        // ---- H-pass: 5 row-tiles cover H rows [base_r-8, base_r+71] ----
        #pragma unroll
        for (int rt = 0; rt < 5; ++rt) {
            const int xoff = (16 * rt + n15) * XS + 16 * w + 8 * quad;  // 16B-al
            uint4 pu, tu, au;
            if (ch != 1 && ch != 3) pu = *(const uint4*)&Xp[xoff];
            if (ch != 0 && ch != 2) tu = *(const uint4*)&Xt[xoff];
            if      (ch == 0) au = pu;
            else if (ch == 1) au = tu;
            else if (ch == 2) au = make_uint4(sqpk(pu.x), sqpk(pu.y), sqpk(pu.z), sqpk(pu.w));
            else if (ch == 3) au = make_uint4(sqpk(tu.x), sqpk(tu.y), sqpk(tu.z), sqpk(tu.w));
            else              au = make_uint4(mulpk(pu.x, tu.x), mulpk(pu.y, tu.y),
                                              mulpk(pu.z, tu.z), mulpk(pu.w, tu.w));
            const bf16x8 afrag = __builtin_bit_cast(bf16x8, au);
            const f32x4 hd = __builtin_amdgcn_mfma_f32_16x16x32_bf16(
                afrag, wfrag, zero4, 0, 0, 0);
            // C-layout: row = 4*quad+reg, col = n15 -> transposed store is b64
            *(uint2*)&Ht[(16 * w + n15) * XS + 16 * rt + 4 * quad] =
                make_uint2(pk2(hd[0], hd[1]), pk2(hd[2], hd[3]));
        }
        // same-wave RAW through LDS: compiler inserts lgkmcnt waits
        // ---- V-pass: 4 output row-tiles, accumulate in registers ----
        #pragma unroll
        for (int rt = 0; rt < 4; ++rt) {
            const bf16x8 bfrag = *(const bf16x8*)&Ht[(16 * w + n15) * XS +
                                                     16 * rt + 8 * quad];
            vacc[ch][rt] = __builtin_amdgcn_mfma_f32_16x16x32_bf16(
                wfrag, bfrag, vacc[ch][rt], 0, 0, 0);
        }
    }

    // ---- SSIM epilogue: 16 pixels per lane ----
    float acc = 0.f;
    #pragma unroll
    for (int rt = 0; rt < 4; ++rt) {
        #pragma unroll
        for (int r = 0; r < 4; ++r) {
            const float mu1 = vacc[0][rt][r], mu2 = vacc[1][rt][r];
            const float e11 = vacc[2][rt][r], e22 = vacc[3][rt][r];
            const float e12 = vacc[4][rt][r];
            const float mu1_sq = mu1 * mu1, mu2_sq = mu2 * mu2;
            const float mu1_mu2 = mu1 * mu2;
            const float s1  = e11 - mu1_sq;
            const float s2  = e22 - mu2_sq;
            const float s12 = e12 - mu1_mu2;
            const float num = (2.f * mu1_mu2 + SSIM_C1) * (2.f * s12 + SSIM_C2);
            const float den = (mu1_sq + mu2_sq + SSIM_C1) * (s1 + s2 + SSIM_C2);
            acc += num * __builtin_amdgcn_rcpf(den);
        }
    }

    // ---- Block reduction ----
    #pragma unroll
    for (int off = 32; off > 0; off >>= 1)
        acc += __shfl_down(acc, off, 64);
    if (lane == 0) wsum[w] = acc;
    __syncthreads();
    if (tid == 0) {
        const int bid = blockIdx.x + gridDim.x * (blockIdx.y + gridDim.y * blockIdx.z);
        partial[bid] = wsum[0] + wsum[1] + wsum[2] + wsum[3];
    }
}

// Reduce 3072 partials -> scalar (double accumulate)
__global__ __launch_bounds__(256) void ssim_reduce_kernel(
    const float* __restrict__ partial, float* __restrict__ out)
{
    const int tid = threadIdx.x;
    float s = 0.f;
    #pragma unroll
    for (int k = 0; k < 12; ++k) s += partial[tid + 256 * k];
    double acc = (double)s;
    #pragma unroll
    for (int off = 32; off > 0; off >>= 1)
        acc += __shfl_down(acc, off, 64);
    __shared__ double wsumd[4];
    const int lane = tid & 63, wid = tid >> 6;
    if (lane == 0) wsumd[wid] = acc;
    __syncthreads();
    if (tid == 0) {
        const double total = wsumd[0] + wsumd[1] + wsumd[2] + wsumd[3];
        const double N = (double)NPLANES * IMG_H * IMG_W;
        out[0] = (float)(1.0 - total / N);
    }
}

extern "C" void kernel_launch(void* const* d_in, const int* in_sizes, int n_in,
                              void* d_out, int out_size, void* d_ws, size_t ws_size,
                              hipStream_t stream)
{
    const float* pred   = (const float*)d_in[0];
    const float* target = (const float*)d_in[1];
    const float* window = (const float*)d_in[2];
    float* out = (float*)d_out;
    float* partial = (float*)d_ws;   // 3072 floats = 12 KiB

    dim3 grid(IMG_W / TILE, IMG_H / TILE, NPLANES);   // (8, 8, 48) = 3072 blocks
    ssim_mfma_kernel<<<grid, 256, 0, stream>>>(pred, target, window, partial);
    ssim_reduce_kernel<<<1, 256, 0, stream>>>(partial, out);
}